// Round 4
// baseline (1116.976 us; speedup 1.0000x reference)
//
#include <hip/hip_runtime.h>
#include <hip/hip_bf16.h>
#include <stdint.h>

// Problem constants: B=2, T=2048, C=4096, H=32, hd=128; M=N=K=4096 for all GEMMs.
typedef __bf16 bf16_t;
typedef __attribute__((ext_vector_type(8))) __bf16 bf16x8;
typedef __attribute__((ext_vector_type(4))) float f32x4;

// async global->LDS, 16B/lane; LDS dest is wave-uniform base + lane*16 (m104).
#define GLL16(gptr, lptr)                                                      \
  __builtin_amdgcn_global_load_lds(                                            \
      (__attribute__((address_space(1))) void*)(gptr),                         \
      (__attribute__((address_space(3))) void*)(lptr), 16, 0, 0)

// ---------------- fused f32 -> bf16 cast for all 5 tensors ----------------
__global__ __launch_bounds__(256) void cast5_kernel(const float* __restrict__ x,
                                                    const float* __restrict__ wq,
                                                    const float* __restrict__ wk,
                                                    const float* __restrict__ wv,
                                                    const float* __restrict__ wo,
                                                    bf16_t* __restrict__ outbase) {
  const size_t SZ = (size_t)4096 * 4096;
  const float* in;
  switch (blockIdx.y) {
    case 0: in = x; break;
    case 1: in = wq; break;
    case 2: in = wk; break;
    case 3: in = wv; break;
    default: in = wo; break;
  }
  bf16_t* out = outbase + (size_t)blockIdx.y * SZ;
  int i = blockIdx.x * 256 + threadIdx.x;  // 8 elems/thread
  const float4* p = (const float4*)in + (size_t)i * 2;
  float4 a = p[0], b = p[1];
  bf16x8 o;
  o[0] = (__bf16)a.x; o[1] = (__bf16)a.y; o[2] = (__bf16)a.z; o[3] = (__bf16)a.w;
  o[4] = (__bf16)b.x; o[5] = (__bf16)b.y; o[6] = (__bf16)b.z; o[7] = (__bf16)b.w;
  *((bf16x8*)out + i) = o;
}

// ============ 256x256 / BK=32 register-pipelined GEMM machinery ============
// LDS: As[2][256*32], Bs[2][256*32] bf16 = 64 KB total (2 bufs, 16 KB/operand).
// XOR swizzle (round-2, verified conflicts -> 0): global k-chunk c of row r
// stored at slot c ^ ((r>>1)&3); reader slot quad ^ ((l15>>1)&3).  Applied on
// the per-lane GLOBAL source address (GLL16 dest linear, m104).
//
// Round-3 post-mortem: per K=32 half, MFMA floor 1242 cyc vs measured 2625 --
// LDS frag reads (96 b128 ~ 1000 cyc) ran SERIALLY with MFMA (conflict-cycle
// delta round1->2 showed through 1:1 = unhidden reads).  This version
// register-pipelines: every ds_read burst is issued immediately before a
// 16-MFMA cluster whose operands are ALREADY in registers, so the read drain
// (~350-700 cyc) shadows under the cluster (~620 cyc).  Per tile j:
//   read af1(j) | MFMA af0(j)xb(j) | lgkm(0) | bar1 (buf j&1 fully read)
//   stage(j+2 -> buf j&1) | vmcnt(4) | bar2 (tile j+1 visible)
//   read af0/b(j+1) | MFMA af1(j)xb(j)
// vmcnt(4): retires stage(j+1) (issued last iter), keeps stage(j+2) in flight.
//
// Stage one 256x32 operand tile (16 KB): 2 x GLL16 per thread; wave w covers
// rows w*32..w*32+31; lane l -> row l>>2, slot l&3; source k-chunk
// (l&3)^((l>>3)&3) == slot ^ ((row>>1)&3).
#define STAGE_HALF(gbase, ldsbase)                                             \
  do {                                                                         \
    GLL16((gbase) + (size_t)(w * 32 + sr) * 4096 + sq, (ldsbase) + w * 1024);  \
    GLL16((gbase) + (size_t)(w * 32 + 16 + sr) * 4096 + sq,                    \
          (ldsbase) + w * 1024 + 512);                                         \
  } while (0)

// 16-MFMA cluster on in-register fragments.  sched_barrier(0) first: pins the
// just-issued ds_reads ABOVE the cluster (they are next-use loads; compiler
// would otherwise sink them), then setprio around the MFMA run.
#define MFMA_CL(ACCB_, AF_, BF_)                                               \
  __builtin_amdgcn_sched_barrier(0);                                           \
  __builtin_amdgcn_s_setprio(1);                                               \
  _Pragma("unroll") for (int mi = 0; mi < 4; ++mi)                             \
      _Pragma("unroll") for (int ni = 0; ni < 4; ++ni)                         \
          acc[(ACCB_) + mi][ni] = __builtin_amdgcn_mfma_f32_16x16x32_bf16(     \
              AF_[mi], BF_[ni], acc[(ACCB_) + mi][ni], 0, 0, 0);               \
  __builtin_amdgcn_s_setprio(0);

// One K-tile (K=32).  P_ = buf (compile-time 0/1).  AF1T_ shared across
// parities (lifetime within one tile).  Correctness of bar1: cluster0's
// operand-waits cover af0/b reads; the explicit lgkm(0) covers af1 reads;
// so at bar1 every wave's reads of buf P_ are complete -> stage may overwrite.
#define KITER(P_, AF0C_, BFC_, AF0N_, BFN_, KT_, MORE_)                        \
  do {                                                                         \
    _Pragma("unroll") for (int mi = 0; mi < 4; ++mi) af1t[mi] =                \
        *(const bf16x8*)&As[P_][(wr * 128 + 64 + mi * 16 + l15) * 32 + sl8];   \
    MFMA_CL(0, AF0C_, BFC_)                                                    \
    asm volatile("s_waitcnt lgkmcnt(0)" ::: "memory");                         \
    __builtin_amdgcn_sched_barrier(0);                                         \
    __builtin_amdgcn_s_barrier(); /* bar1: buf P_ fully read by all waves */   \
    if (MORE_) {                                                               \
      STAGE_HALF(Ag + (size_t)(KT_ + 2) * 32, &As[P_][0]);                     \
      STAGE_HALF(Bg + (size_t)(KT_ + 2) * 32, &Bs[P_][0]);                     \
      asm volatile("s_waitcnt vmcnt(4)" ::: "memory");                         \
    } else {                                                                   \
      asm volatile("s_waitcnt vmcnt(0)" ::: "memory");                         \
    }                                                                          \
    __builtin_amdgcn_s_barrier(); /* bar2: tile KT_+1 visible */               \
    _Pragma("unroll") for (int ni = 0; ni < 4; ++ni) BFN_[ni] =                \
        *(const bf16x8*)&Bs[P_ ^ 1][(wc * 64 + ni * 16 + l15) * 32 + sl8];     \
    _Pragma("unroll") for (int mi = 0; mi < 4; ++mi) AF0N_[mi] =               \
        *(const bf16x8*)&As[P_ ^ 1][(wr * 128 + mi * 16 + l15) * 32 + sl8];    \
    MFMA_CL(4, af1t, BFC_)                                                     \
  } while (0)

// Main loop: 128 K-tiles, manually unrolled x2 for static buf parity and
// static register double-buffering (rule #20: no runtime-indexed frag arrays).
#define GEMM256_MAIN(Aptr, Bptr)                                               \
  const bf16_t* Ag = (Aptr) + (size_t)bm * 4096;                               \
  const bf16_t* Bg = (Bptr) + (size_t)bn * 4096;                               \
  f32x4 acc[8][4] = {};                                                        \
  bf16x8 af0A[4], af0B[4], bfA[4], bfB[4], af1t[4];                            \
  STAGE_HALF(Ag, &As[0][0]);                                                   \
  STAGE_HALF(Bg, &Bs[0][0]);                                                   \
  STAGE_HALF(Ag + 32, &As[1][0]);                                              \
  STAGE_HALF(Bg + 32, &Bs[1][0]);                                              \
  asm volatile("s_waitcnt vmcnt(4)" ::: "memory"); /* tile0 landed */          \
  __builtin_amdgcn_s_barrier();                                                \
  _Pragma("unroll") for (int ni = 0; ni < 4; ++ni) bfA[ni] =                   \
      *(const bf16x8*)&Bs[0][(wc * 64 + ni * 16 + l15) * 32 + sl8];            \
  _Pragma("unroll") for (int mi = 0; mi < 4; ++mi) af0A[mi] =                  \
      *(const bf16x8*)&As[0][(wr * 128 + mi * 16 + l15) * 32 + sl8];           \
  for (int jj = 0; jj < 64; ++jj) {                                            \
    const int kt = jj * 2;                                                     \
    const bool m = (jj < 63);                                                  \
    KITER(0, af0A, bfA, af0B, bfB, kt, m);                                     \
    KITER(1, af0B, bfB, af0A, bfA, kt + 1, m);                                 \
  }

// ---------------- epilogues (8x4 accumulator geometry) ----------------
// C/D fragment mapping (16x16x32): row = quad*4 + reg, col = lane&15.
// acc index a: a<4 -> rows wr*128 + a*16 (af0 block); a>=4 -> +64 (af1 block).
__device__ __forceinline__ void epi_rope256(const f32x4 (&acc)[8][4],
                                            bf16_t* __restrict__ C, int bm,
                                            int bn, int wr, int wc, int quad,
                                            int l15) {
#pragma unroll
  for (int a = 0; a < 8; ++a) {
    const int row0 = bm + wr * 128 + (a & 3) * 16 + (a >> 2) * 64 + quad * 4;
    float fsv[4], fcv[4];
#pragma unroll
    for (int r = 0; r < 4; ++r)
      sincosf((float)((row0 + r) & 2047), &fsv[r], &fcv[r]);
#pragma unroll
    for (int ni = 0; ni < 4; ++ni) {
      const int col = bn + wc * 64 + ni * 16 + l15;
      const bool odd = (col & 1);
#pragma unroll
      for (int r = 0; r < 4; ++r) {
        float v = acc[a][ni][r];
        float pr = __shfl_xor(v, 1, 64);  // RoPE pair partner: adjacent col
        float o = odd ? (pr * fsv[r] + v * fcv[r]) : (v * fcv[r] - pr * fsv[r]);
        C[(size_t)(row0 + r) * 4096 + col] = (__bf16)o;
      }
    }
  }
}

__device__ __forceinline__ void epi_vt256(const f32x4 (&acc)[8][4],
                                          bf16_t* __restrict__ VT, int bm,
                                          int bn, int wr, int wc, int quad,
                                          int l15) {
#pragma unroll
  for (int a = 0; a < 8; ++a) {
    const int row0 = bm + wr * 128 + (a & 3) * 16 + (a >> 2) * 64 + quad * 4;
    const int b = row0 >> 11, t0 = row0 & 2047;
#pragma unroll
    for (int ni = 0; ni < 4; ++ni) {
      const int col = bn + wc * 64 + ni * 16 + l15;
      const int h = col >> 7, d = col & 127;
      union { __bf16 e[4]; uint2 u; } pk;
#pragma unroll
      for (int r = 0; r < 4; ++r) pk.e[r] = (__bf16)acc[a][ni][r];
      *(uint2*)&VT[((size_t)((b * 32 + h) * 128 + d)) * 2048 + t0] = pk.u;
    }
  }
}

// ---------------- fused QKV projection: grid (256, 3) ----------------
// blockIdx.y selects matrix: 0=Q (RoPE), 1=K (RoPE), 2=V (transposed store).
__global__ __launch_bounds__(512, 2) void gemm_qkv(const bf16_t* __restrict__ X,
                                                   const bf16_t* __restrict__ WQ,
                                                   const bf16_t* __restrict__ WK,
                                                   const bf16_t* __restrict__ WV,
                                                   bf16_t* __restrict__ Qo,
                                                   bf16_t* __restrict__ Ko,
                                                   bf16_t* __restrict__ VTo) {
  __shared__ bf16_t As[2][8192];  // 32 KB
  __shared__ bf16_t Bs[2][8192];  // 32 KB
  const int tid = threadIdx.x;
  const int w = tid >> 6;
  const int lane = tid & 63;
  const int quad = lane >> 4;
  const int l15 = lane & 15;
  const int wr = w >> 2, wc = w & 3;              // 2M x 4N wave grid
  const int sr = lane >> 2;                       // stage row within 16
  const int sq = (((lane & 3) ^ ((lane >> 3) & 3))) * 8;  // swizzled k-chunk
  const int sl8 = (quad ^ ((l15 >> 1) & 3)) * 8;  // swizzled read slot
  const int mat = blockIdx.y;
  int id = blockIdx.x;
  id = (id & 7) * 32 + (id >> 3);  // XCD-aware swizzle (bijective: 256%8==0)
  const int bm = (id >> 4) * 256, bn = (id & 15) * 256;
  const bf16_t* Bp = (mat == 0) ? WQ : (mat == 1) ? WK : WV;

  GEMM256_MAIN(X, Bp)

  if (mat == 0)
    epi_rope256(acc, Qo, bm, bn, wr, wc, quad, l15);
  else if (mat == 1)
    epi_rope256(acc, Ko, bm, bn, wr, wc, quad, l15);
  else
    epi_vt256(acc, VTo, bm, bn, wr, wc, quad, l15);
}

// ---------------- output projection GEMM: f32 C row-major ----------------
__global__ __launch_bounds__(512, 2) void gemm_out(const bf16_t* __restrict__ A,
                                                   const bf16_t* __restrict__ B,
                                                   float* __restrict__ C) {
  __shared__ bf16_t As[2][8192];
  __shared__ bf16_t Bs[2][8192];
  const int tid = threadIdx.x;
  const int w = tid >> 6;
  const int lane = tid & 63;
  const int quad = lane >> 4;
  const int l15 = lane & 15;
  const int wr = w >> 2, wc = w & 3;
  const int sr = lane >> 2;
  const int sq = (((lane & 3) ^ ((lane >> 3) & 3))) * 8;
  const int sl8 = (quad ^ ((l15 >> 1) & 3)) * 8;
  int id = blockIdx.x;
  id = (id & 7) * 32 + (id >> 3);
  const int bm = (id >> 4) * 256, bn = (id & 15) * 256;

  GEMM256_MAIN(A, B)

#pragma unroll
  for (int a = 0; a < 8; ++a) {
    const int row0 = bm + wr * 128 + (a & 3) * 16 + (a >> 2) * 64 + quad * 4;
#pragma unroll
    for (int ni = 0; ni < 4; ++ni) {
      const int col = bn + wc * 64 + ni * 16 + l15;
#pragma unroll
      for (int r = 0; r < 4; ++r)
        C[(size_t)(row0 + r) * 4096 + col] = acc[a][ni][r];
    }
  }
}

// ---------------- flash attention: 64x64 tiles, online softmax ----------------
// (unchanged this round)
__global__ __launch_bounds__(256) void attn_kernel(const bf16_t* __restrict__ Q,
                                                   const bf16_t* __restrict__ Km,
                                                   const bf16_t* __restrict__ VT,
                                                   bf16_t* __restrict__ O) {
  __shared__ bf16_t Ks[64 * 128];    // 16 KB, swizzled
  __shared__ bf16_t Vts[128 * 64];   // 16 KB, swizzled
  __shared__ bf16_t QPs[64 * 128];   // 16 KB: Q staging, then P staging (reuse)
  const int tid = threadIdx.x;
  const int w = tid >> 6;
  const int lane = tid & 63;
  const int quad = lane >> 4;
  const int l15 = lane & 15;
  const int bh = blockIdx.x;             // 0..63
  const int qtile = 31 - blockIdx.y;     // heavy tiles first (load balance)
  const int mrow_base = (bh >> 5) * 2048;
  const int h = bh & 31;
  const float scale = 0.08838834764831845f;  // 128^-0.5

#pragma unroll
  for (int it = 0; it < 4; ++it) {
    int c = w * 4 + it;                 // 1KB chunk-group = 4 rows
    int row = c * 4 + (lane >> 4);
    int cc = (lane & 15) ^ (row & 15);  // global chunk for this lane's slot
    GLL16(Q + (size_t)(mrow_base + qtile * 64 + row) * 4096 + h * 128 + cc * 8,
          &QPs[c * 512]);
  }
  __syncthreads();
  bf16x8 qf[4];  // wave's 16 q-rows, full hd=128, kept in regs
#pragma unroll
  for (int ks = 0; ks < 4; ++ks) {
    int row = w * 16 + l15;
    int slot = (ks * 4 + quad) ^ (row & 15);
    qf[ks] = *(const bf16x8*)&QPs[row * 128 + slot * 8];
  }
  bf16_t* Pw = &QPs[w * 16 * 72];  // wave-private P: 16 rows, stride 72 (pad)

  f32x4 accO[8] = {};
  float mrun[4], lrun[4];
#pragma unroll
  for (int r = 0; r < 4; ++r) { mrun[r] = -1e30f; lrun[r] = 0.f; }

  for (int kt = 0; kt <= qtile; ++kt) {
    __syncthreads();
#pragma unroll
    for (int it = 0; it < 4; ++it) {
      int c = w * 4 + it;
      int krow = c * 4 + (lane >> 4);
      int kcc = (lane & 15) ^ (krow & 15);
      GLL16(Km + (size_t)(mrow_base + kt * 64 + krow) * 4096 + h * 128 + kcc * 8,
            &Ks[c * 512]);
      int vrow = c * 8 + (lane >> 3);
      int vcc = (lane & 7) ^ (vrow & 7);
      GLL16(VT + (size_t)(bh * 128 + vrow) * 2048 + kt * 64 + vcc * 8,
            &Vts[c * 512]);
    }
    __syncthreads();

    f32x4 s[4];
#pragma unroll
    for (int ni = 0; ni < 4; ++ni) {
      s[ni] = (f32x4){0.f, 0.f, 0.f, 0.f};
#pragma unroll
      for (int ks = 0; ks < 4; ++ks) {
        int row = ni * 16 + l15;
        int slot = (ks * 4 + quad) ^ (row & 15);
        bf16x8 kf = *(const bf16x8*)&Ks[row * 128 + slot * 8];
        s[ni] = __builtin_amdgcn_mfma_f32_16x16x32_bf16(qf[ks], kf, s[ni], 0, 0, 0);
      }
    }
    const bool diag = (kt == qtile);
#pragma unroll
    for (int ni = 0; ni < 4; ++ni)
#pragma unroll
      for (int r = 0; r < 4; ++r) {
        float v = s[ni][r] * scale;
        if (diag && (ni * 16 + l15) > (w * 16 + quad * 4 + r)) v = -1e30f;
        s[ni][r] = v;
      }
    float mx[4], alpha[4], rs[4];
#pragma unroll
    for (int r = 0; r < 4; ++r)
      mx[r] = fmaxf(fmaxf(s[0][r], s[1][r]), fmaxf(s[2][r], s[3][r]));
#pragma unroll
    for (int off = 1; off < 16; off <<= 1)
#pragma unroll
      for (int r = 0; r < 4; ++r) mx[r] = fmaxf(mx[r], __shfl_xor(mx[r], off, 64));
    float ps[4][4];
#pragma unroll
    for (int r = 0; r < 4; ++r) {
      float mn = fmaxf(mrun[r], mx[r]);
      alpha[r] = __expf(mrun[r] - mn);
      mrun[r] = mn;
      rs[r] = 0.f;
    }
#pragma unroll
    for (int ni = 0; ni < 4; ++ni)
#pragma unroll
      for (int r = 0; r < 4; ++r) {
        float p = __expf(s[ni][r] - mrun[r]);
        ps[ni][r] = p;
        rs[r] += p;
      }
#pragma unroll
    for (int off = 1; off < 16; off <<= 1)
#pragma unroll
      for (int r = 0; r < 4; ++r) rs[r] += __shfl_xor(rs[r], off, 64);
#pragma unroll
    for (int r = 0; r < 4; ++r) lrun[r] = lrun[r] * alpha[r] + rs[r];
#pragma unroll
    for (int nt = 0; nt < 8; ++nt)
#pragma unroll
      for (int r = 0; r < 4; ++r) accO[nt][r] *= alpha[r];
#pragma unroll
    for (int ni = 0; ni < 4; ++ni)
#pragma unroll
      for (int r = 0; r < 4; ++r)
        Pw[(quad * 4 + r) * 72 + ni * 16 + l15] = (__bf16)ps[ni][r];
    asm volatile("s_waitcnt lgkmcnt(0)" ::: "memory");
    bf16x8 pf[2];
#pragma unroll
    for (int ks = 0; ks < 2; ++ks)
      pf[ks] = *(const bf16x8*)&Pw[l15 * 72 + ks * 32 + quad * 8];
#pragma unroll
    for (int nt = 0; nt < 8; ++nt)
#pragma unroll
      for (int ks = 0; ks < 2; ++ks) {
        int vrow = nt * 16 + l15;
        int slot = (ks * 4 + quad) ^ (vrow & 7);
        bf16x8 vf = *(const bf16x8*)&Vts[vrow * 64 + slot * 8];
        accO[nt] = __builtin_amdgcn_mfma_f32_16x16x32_bf16(pf[ks], vf, accO[nt], 0, 0, 0);
      }
  }

#pragma unroll
  for (int r = 0; r < 4; ++r) lrun[r] = 1.f / lrun[r];
#pragma unroll
  for (int nt = 0; nt < 8; ++nt)
#pragma unroll
    for (int r = 0; r < 4; ++r) {
      int trow = qtile * 64 + w * 16 + quad * 4 + r;
      int d = nt * 16 + l15;
      O[(size_t)(mrow_base + trow) * 4096 + h * 128 + d] =
          (__bf16)(accO[nt][r] * lrun[r]);
    }
}

extern "C" void kernel_launch(void* const* d_in, const int* in_sizes, int n_in,
                              void* d_out, int out_size, void* d_ws, size_t ws_size,
                              hipStream_t stream) {
  (void)in_sizes; (void)n_in; (void)out_size; (void)ws_size;
  const float* x = (const float*)d_in[0];
  const float* wq = (const float*)d_in[1];
  const float* wk = (const float*)d_in[2];
  const float* wv = (const float*)d_in[3];
  const float* wo = (const float*)d_in[4];
  float* out = (float*)d_out;

  const size_t SZ = (size_t)4096 * 4096;  // 16M elems; 9 bf16 arrays = 288 MB ws
  bf16_t* xb = (bf16_t*)d_ws;
  bf16_t* wqb = xb + SZ;
  bf16_t* wkb = wqb + SZ;
  bf16_t* wvb = wkb + SZ;
  bf16_t* wob = wvb + SZ;
  bf16_t* qb = wob + SZ;
  bf16_t* kb = qb + SZ;
  bf16_t* vtb = kb + SZ;
  bf16_t* ab = vtb + SZ;

  dim3 b256(256), b512(512);
  cast5_kernel<<<dim3((unsigned)(SZ / 8 / 256), 5), b256, 0, stream>>>(
      x, wq, wk, wv, wo, xb);

  gemm_qkv<<<dim3(256, 3), b512, 0, stream>>>(xb, wqb, wkb, wvb, qb, kb, vtb);

  attn_kernel<<<dim3(64, 32), b256, 0, stream>>>(qb, kb, vtb, ab);

  gemm_out<<<dim3(256), b512, 0, stream>>>(ab, wob, out);
}

// Round 5
// 978.738 us; speedup vs baseline: 1.1412x; 1.1412x over previous
//
#include <hip/hip_runtime.h>
#include <hip/hip_bf16.h>
#include <stdint.h>

// Problem constants: B=2, T=2048, C=4096, H=32, hd=128; M=N=K=4096 for all GEMMs.
typedef __bf16 bf16_t;
typedef __attribute__((ext_vector_type(8))) __bf16 bf16x8;
typedef __attribute__((ext_vector_type(4))) float f32x4;

// async global->LDS, 16B/lane; LDS dest is wave-uniform base + lane*16 (m104).
#define GLL16(gptr, lptr)                                                      \
  __builtin_amdgcn_global_load_lds(                                            \
      (__attribute__((address_space(1))) void*)(gptr),                         \
      (__attribute__((address_space(3))) void*)(lptr), 16, 0, 0)

// ---------------- fused f32 -> bf16 cast for all 5 tensors ----------------
__global__ __launch_bounds__(256) void cast5_kernel(const float* __restrict__ x,
                                                    const float* __restrict__ wq,
                                                    const float* __restrict__ wk,
                                                    const float* __restrict__ wv,
                                                    const float* __restrict__ wo,
                                                    bf16_t* __restrict__ outbase) {
  const size_t SZ = (size_t)4096 * 4096;
  const float* in;
  switch (blockIdx.y) {
    case 0: in = x; break;
    case 1: in = wq; break;
    case 2: in = wk; break;
    case 3: in = wv; break;
    default: in = wo; break;
  }
  bf16_t* out = outbase + (size_t)blockIdx.y * SZ;
  int i = blockIdx.x * 256 + threadIdx.x;  // 8 elems/thread
  const float4* p = (const float4*)in + (size_t)i * 2;
  float4 a = p[0], b = p[1];
  bf16x8 o;
  o[0] = (__bf16)a.x; o[1] = (__bf16)a.y; o[2] = (__bf16)a.z; o[3] = (__bf16)a.w;
  o[4] = (__bf16)b.x; o[5] = (__bf16)b.y; o[6] = (__bf16)b.z; o[7] = (__bf16)b.w;
  *((bf16x8*)out + i) = o;
}

// ========== 256x256 / BK=32 ring-4 pipelined GEMM machinery ==========
// LDS: As[4][256*32], Bs[4][256*32] bf16 = 128 KB (ring of 4 K=32 tiles).
// XOR swizzle (round-2, verified conflicts -> 0): global k-chunk c of row r
// stored at slot c ^ ((r>>1)&3); reader slot quad ^ ((l15>>1)&3).  Applied on
// the per-lane GLOBAL source address (GLL16 dest linear, m104).
//
// Round-4 post-mortem: BK=32 with 2 barriers/step + 1-step vmem prefetch
// distance REGRESSED (vmcnt waited on loads younger than HBM latency).
// This version keeps round-3's economics (1 barrier per K=32, 3-step
// prefetch = ~4000 cyc >> miss latency, vmcnt(8) always satisfied) and
// overlaps ALL frag reads under MFMA:
//   step j (slot s=j&3):
//     read af1(j) [4 ds]                      -> drains under cluster0
//     lgkmcnt(4)  [bf(j),af0(j) landed; af1 in flight]
//     cluster0: acc[0..3] += af0(j) x bf(j)
//     stage tile j+3 -> slot (j-1)&3 [4 GLL]
//     lgkmcnt(0); vmcnt(8) [tile j+1 certified]; s_barrier
//     read bf(j+1), af0(j+1) from slot (j+1)&3 [8 ds] -> drain under cluster1
//     cluster1: acc[4..7] += af1(j) x bf(j)
// Hazard proof: all reads of slot (j-1)&3 are lgkm-drained before the
// (j-1)->j barrier; step-j stage writes that slot only after that barrier.
// Reads of slot (j+1)&3 follow step-j's barrier, which collects every
// wave's own vmcnt(8) retiring tile j+1's GLLs.
//
// Stage one 256x32 operand tile (16 KB): 2 x GLL16 per thread; wave w covers
// rows w*32..w*32+31; lane l -> row l>>2, slot l&3; source k-chunk
// (l&3)^((l>>3)&3) == slot ^ ((row>>1)&3).
#define STAGE_HALF(gbase, ldsbase)                                             \
  do {                                                                         \
    GLL16((gbase) + (size_t)(w * 32 + sr) * 4096 + sq, (ldsbase) + w * 1024);  \
    GLL16((gbase) + (size_t)(w * 32 + 16 + sr) * 4096 + sq,                    \
          (ldsbase) + w * 1024 + 512);                                         \
  } while (0)

#define MFMA16(ACCB_, AF_, BF_)                                                \
  _Pragma("unroll") for (int mi = 0; mi < 4; ++mi)                             \
      _Pragma("unroll") for (int ni = 0; ni < 4; ++ni)                         \
          acc[(ACCB_) + mi][ni] = __builtin_amdgcn_mfma_f32_16x16x32_bf16(     \
              AF_[mi], BF_[ni], acc[(ACCB_) + mi][ni], 0, 0, 0)

// One K=32 step.  SLOT_ compile-time; AFC_/BFC_ current frags (loaded last
// step), AFN_/BFN_ next-step frags (loaded here).  sched_barrier(0) fences
// pin each region (rule #18: hipcc hoists register-only MFMA past inline-asm
// waits despite "memory" clobber).
#define KSTEP(SLOT_, AFC_, BFC_, AFN_, BFN_, STAGE_STMT, VMCNT_STMT, LAST_)    \
  do {                                                                         \
    _Pragma("unroll") for (int mi = 0; mi < 4; ++mi) af1t[mi] =                \
        *(const bf16x8*)&As[SLOT_][(wr * 128 + 64 + mi * 16 + l15) * 32 + sl8];\
    asm volatile("s_waitcnt lgkmcnt(4)" ::: "memory");                         \
    __builtin_amdgcn_sched_barrier(0);                                         \
    __builtin_amdgcn_s_setprio(1);                                             \
    MFMA16(0, AFC_, BFC_);                                                     \
    __builtin_amdgcn_s_setprio(0);                                             \
    __builtin_amdgcn_sched_barrier(0);                                         \
    STAGE_STMT;                                                                \
    asm volatile("s_waitcnt lgkmcnt(0)" ::: "memory");                         \
    VMCNT_STMT;                                                                \
    __builtin_amdgcn_sched_barrier(0);                                         \
    if (!(LAST_)) {                                                            \
      __builtin_amdgcn_s_barrier();                                            \
      _Pragma("unroll") for (int ni = 0; ni < 4; ++ni) BFN_[ni] =              \
          *(const bf16x8*)&Bs[(SLOT_ + 1) & 3][(wc * 64 + ni * 16 + l15) * 32 +\
                                               sl8];                           \
      _Pragma("unroll") for (int mi = 0; mi < 4; ++mi) AFN_[mi] =              \
          *(const bf16x8*)&As[(SLOT_ + 1) & 3][(wr * 128 + mi * 16 + l15) * 32 \
                                               + sl8];                         \
    }                                                                          \
    __builtin_amdgcn_sched_barrier(0);                                         \
    __builtin_amdgcn_s_setprio(1);                                             \
    MFMA16(4, af1t, BFC_);                                                     \
    __builtin_amdgcn_s_setprio(0);                                             \
  } while (0)

// 128 K=32 steps.  Prologue stages tiles 0,1,2; steady state stages j+3 and
// waits vmcnt(8) (outstanding = tiles j+1,j+2,j+3 = 12 GLLs; retire j+1).
// Tail (j=124..127): 124 stages tile 127 / vmcnt(8); 125 vmcnt(4);
// 126 vmcnt(0); 127 clusters only (LAST).
#define GEMM256_MAIN(Aptr, Bptr)                                               \
  const bf16_t* Ag = (Aptr) + (size_t)bm * 4096;                               \
  const bf16_t* Bg = (Bptr) + (size_t)bn * 4096;                               \
  f32x4 acc[8][4] = {};                                                        \
  bf16x8 af0A[4], af0B[4], bfA[4], bfB[4], af1t[4];                            \
  STAGE_HALF(Ag, &As[0][0]);                                                   \
  STAGE_HALF(Bg, &Bs[0][0]);                                                   \
  STAGE_HALF(Ag + 32, &As[1][0]);                                              \
  STAGE_HALF(Bg + 32, &Bs[1][0]);                                              \
  STAGE_HALF(Ag + 64, &As[2][0]);                                              \
  STAGE_HALF(Bg + 64, &Bs[2][0]);                                              \
  asm volatile("s_waitcnt vmcnt(8)" ::: "memory"); /* tile0 landed */          \
  __builtin_amdgcn_s_barrier();                                                \
  _Pragma("unroll") for (int ni = 0; ni < 4; ++ni) bfA[ni] =                   \
      *(const bf16x8*)&Bs[0][(wc * 64 + ni * 16 + l15) * 32 + sl8];            \
  _Pragma("unroll") for (int mi = 0; mi < 4; ++mi) af0A[mi] =                  \
      *(const bf16x8*)&As[0][(wr * 128 + mi * 16 + l15) * 32 + sl8];           \
  for (int jj = 0; jj < 31; ++jj) {                                            \
    const int kt = jj * 4;                                                     \
    KSTEP(0, af0A, bfA, af0B, bfB,                                             \
          { STAGE_HALF(Ag + (size_t)(kt + 3) * 32, &As[3][0]);                 \
            STAGE_HALF(Bg + (size_t)(kt + 3) * 32, &Bs[3][0]); },              \
          asm volatile("s_waitcnt vmcnt(8)" ::: "memory"), 0);                 \
    KSTEP(1, af0B, bfB, af0A, bfA,                                             \
          { STAGE_HALF(Ag + (size_t)(kt + 4) * 32, &As[0][0]);                 \
            STAGE_HALF(Bg + (size_t)(kt + 4) * 32, &Bs[0][0]); },              \
          asm volatile("s_waitcnt vmcnt(8)" ::: "memory"), 0);                 \
    KSTEP(2, af0A, bfA, af0B, bfB,                                             \
          { STAGE_HALF(Ag + (size_t)(kt + 5) * 32, &As[1][0]);                 \
            STAGE_HALF(Bg + (size_t)(kt + 5) * 32, &Bs[1][0]); },              \
          asm volatile("s_waitcnt vmcnt(8)" ::: "memory"), 0);                 \
    KSTEP(3, af0B, bfB, af0A, bfA,                                             \
          { STAGE_HALF(Ag + (size_t)(kt + 6) * 32, &As[2][0]);                 \
            STAGE_HALF(Bg + (size_t)(kt + 6) * 32, &Bs[2][0]); },              \
          asm volatile("s_waitcnt vmcnt(8)" ::: "memory"), 0);                 \
  }                                                                            \
  KSTEP(0, af0A, bfA, af0B, bfB,                                               \
        { STAGE_HALF(Ag + (size_t)127 * 32, &As[3][0]);                        \
          STAGE_HALF(Bg + (size_t)127 * 32, &Bs[3][0]); },                     \
        asm volatile("s_waitcnt vmcnt(8)" ::: "memory"), 0); /* j=124 */       \
  KSTEP(1, af0B, bfB, af0A, bfA, (void)0,                                      \
        asm volatile("s_waitcnt vmcnt(4)" ::: "memory"), 0); /* j=125 */       \
  KSTEP(2, af0A, bfA, af0B, bfB, (void)0,                                      \
        asm volatile("s_waitcnt vmcnt(0)" ::: "memory"), 0); /* j=126 */       \
  KSTEP(3, af0B, bfB, af0A, bfA, (void)0, (void)0, 1);       /* j=127 */

// ---------------- epilogues (8x4 accumulator geometry) ----------------
// C/D fragment mapping (16x16x32): row = quad*4 + reg, col = lane&15.
// acc index a: a<4 -> rows wr*128 + a*16 (af0 block); a>=4 -> +64 (af1 block).
__device__ __forceinline__ void epi_rope256(const f32x4 (&acc)[8][4],
                                            bf16_t* __restrict__ C, int bm,
                                            int bn, int wr, int wc, int quad,
                                            int l15) {
#pragma unroll
  for (int a = 0; a < 8; ++a) {
    const int row0 = bm + wr * 128 + (a & 3) * 16 + (a >> 2) * 64 + quad * 4;
    float fsv[4], fcv[4];
#pragma unroll
    for (int r = 0; r < 4; ++r)
      sincosf((float)((row0 + r) & 2047), &fsv[r], &fcv[r]);
#pragma unroll
    for (int ni = 0; ni < 4; ++ni) {
      const int col = bn + wc * 64 + ni * 16 + l15;
      const bool odd = (col & 1);
#pragma unroll
      for (int r = 0; r < 4; ++r) {
        float v = acc[a][ni][r];
        float pr = __shfl_xor(v, 1, 64);  // RoPE pair partner: adjacent col
        float o = odd ? (pr * fsv[r] + v * fcv[r]) : (v * fcv[r] - pr * fsv[r]);
        C[(size_t)(row0 + r) * 4096 + col] = (__bf16)o;
      }
    }
  }
}

__device__ __forceinline__ void epi_vt256(const f32x4 (&acc)[8][4],
                                          bf16_t* __restrict__ VT, int bm,
                                          int bn, int wr, int wc, int quad,
                                          int l15) {
#pragma unroll
  for (int a = 0; a < 8; ++a) {
    const int row0 = bm + wr * 128 + (a & 3) * 16 + (a >> 2) * 64 + quad * 4;
    const int b = row0 >> 11, t0 = row0 & 2047;
#pragma unroll
    for (int ni = 0; ni < 4; ++ni) {
      const int col = bn + wc * 64 + ni * 16 + l15;
      const int h = col >> 7, d = col & 127;
      union { __bf16 e[4]; uint2 u; } pk;
#pragma unroll
      for (int r = 0; r < 4; ++r) pk.e[r] = (__bf16)acc[a][ni][r];
      *(uint2*)&VT[((size_t)((b * 32 + h) * 128 + d)) * 2048 + t0] = pk.u;
    }
  }
}

// ---------------- fused QKV projection: grid (256, 3) ----------------
// blockIdx.y selects matrix: 0=Q (RoPE), 1=K (RoPE), 2=V (transposed store).
__global__ __launch_bounds__(512, 2) void gemm_qkv(const bf16_t* __restrict__ X,
                                                   const bf16_t* __restrict__ WQ,
                                                   const bf16_t* __restrict__ WK,
                                                   const bf16_t* __restrict__ WV,
                                                   bf16_t* __restrict__ Qo,
                                                   bf16_t* __restrict__ Ko,
                                                   bf16_t* __restrict__ VTo) {
  __shared__ bf16_t As[4][8192];  // 64 KB (ring of 4 K=32 tiles)
  __shared__ bf16_t Bs[4][8192];  // 64 KB
  const int tid = threadIdx.x;
  const int w = tid >> 6;
  const int lane = tid & 63;
  const int quad = lane >> 4;
  const int l15 = lane & 15;
  const int wr = w >> 2, wc = w & 3;              // 2M x 4N wave grid
  const int sr = lane >> 2;                       // stage row within 16
  const int sq = (((lane & 3) ^ ((lane >> 3) & 3))) * 8;  // swizzled k-chunk
  const int sl8 = (quad ^ ((l15 >> 1) & 3)) * 8;  // swizzled read slot
  const int mat = blockIdx.y;
  int id = blockIdx.x;
  id = (id & 7) * 32 + (id >> 3);  // XCD-aware swizzle (bijective: 256%8==0)
  const int bm = (id >> 4) * 256, bn = (id & 15) * 256;
  const bf16_t* Bp = (mat == 0) ? WQ : (mat == 1) ? WK : WV;

  GEMM256_MAIN(X, Bp)

  if (mat == 0)
    epi_rope256(acc, Qo, bm, bn, wr, wc, quad, l15);
  else if (mat == 1)
    epi_rope256(acc, Ko, bm, bn, wr, wc, quad, l15);
  else
    epi_vt256(acc, VTo, bm, bn, wr, wc, quad, l15);
}

// ---------------- output projection GEMM: f32 C row-major ----------------
__global__ __launch_bounds__(512, 2) void gemm_out(const bf16_t* __restrict__ A,
                                                   const bf16_t* __restrict__ B,
                                                   float* __restrict__ C) {
  __shared__ bf16_t As[4][8192];
  __shared__ bf16_t Bs[4][8192];
  const int tid = threadIdx.x;
  const int w = tid >> 6;
  const int lane = tid & 63;
  const int quad = lane >> 4;
  const int l15 = lane & 15;
  const int wr = w >> 2, wc = w & 3;
  const int sr = lane >> 2;
  const int sq = (((lane & 3) ^ ((lane >> 3) & 3))) * 8;
  const int sl8 = (quad ^ ((l15 >> 1) & 3)) * 8;
  int id = blockIdx.x;
  id = (id & 7) * 32 + (id >> 3);
  const int bm = (id >> 4) * 256, bn = (id & 15) * 256;

  GEMM256_MAIN(A, B)

#pragma unroll
  for (int a = 0; a < 8; ++a) {
    const int row0 = bm + wr * 128 + (a & 3) * 16 + (a >> 2) * 64 + quad * 4;
#pragma unroll
    for (int ni = 0; ni < 4; ++ni) {
      const int col = bn + wc * 64 + ni * 16 + l15;
#pragma unroll
      for (int r = 0; r < 4; ++r)
        C[(size_t)(row0 + r) * 4096 + col] = acc[a][ni][r];
    }
  }
}

// ---------------- flash attention: 64x64 tiles, online softmax ----------------
// (unchanged this round)
__global__ __launch_bounds__(256) void attn_kernel(const bf16_t* __restrict__ Q,
                                                   const bf16_t* __restrict__ Km,
                                                   const bf16_t* __restrict__ VT,
                                                   bf16_t* __restrict__ O) {
  __shared__ bf16_t Ks[64 * 128];    // 16 KB, swizzled
  __shared__ bf16_t Vts[128 * 64];   // 16 KB, swizzled
  __shared__ bf16_t QPs[64 * 128];   // 16 KB: Q staging, then P staging (reuse)
  const int tid = threadIdx.x;
  const int w = tid >> 6;
  const int lane = tid & 63;
  const int quad = lane >> 4;
  const int l15 = lane & 15;
  const int bh = blockIdx.x;             // 0..63
  const int qtile = 31 - blockIdx.y;     // heavy tiles first (load balance)
  const int mrow_base = (bh >> 5) * 2048;
  const int h = bh & 31;
  const float scale = 0.08838834764831845f;  // 128^-0.5

#pragma unroll
  for (int it = 0; it < 4; ++it) {
    int c = w * 4 + it;                 // 1KB chunk-group = 4 rows
    int row = c * 4 + (lane >> 4);
    int cc = (lane & 15) ^ (row & 15);  // global chunk for this lane's slot
    GLL16(Q + (size_t)(mrow_base + qtile * 64 + row) * 4096 + h * 128 + cc * 8,
          &QPs[c * 512]);
  }
  __syncthreads();
  bf16x8 qf[4];  // wave's 16 q-rows, full hd=128, kept in regs
#pragma unroll
  for (int ks = 0; ks < 4; ++ks) {
    int row = w * 16 + l15;
    int slot = (ks * 4 + quad) ^ (row & 15);
    qf[ks] = *(const bf16x8*)&QPs[row * 128 + slot * 8];
  }
  bf16_t* Pw = &QPs[w * 16 * 72];  // wave-private P: 16 rows, stride 72 (pad)

  f32x4 accO[8] = {};
  float mrun[4], lrun[4];
#pragma unroll
  for (int r = 0; r < 4; ++r) { mrun[r] = -1e30f; lrun[r] = 0.f; }

  for (int kt = 0; kt <= qtile; ++kt) {
    __syncthreads();
#pragma unroll
    for (int it = 0; it < 4; ++it) {
      int c = w * 4 + it;
      int krow = c * 4 + (lane >> 4);
      int kcc = (lane & 15) ^ (krow & 15);
      GLL16(Km + (size_t)(mrow_base + kt * 64 + krow) * 4096 + h * 128 + kcc * 8,
            &Ks[c * 512]);
      int vrow = c * 8 + (lane >> 3);
      int vcc = (lane & 7) ^ (vrow & 7);
      GLL16(VT + (size_t)(bh * 128 + vrow) * 2048 + kt * 64 + vcc * 8,
            &Vts[c * 512]);
    }
    __syncthreads();

    f32x4 s[4];
#pragma unroll
    for (int ni = 0; ni < 4; ++ni) {
      s[ni] = (f32x4){0.f, 0.f, 0.f, 0.f};
#pragma unroll
      for (int ks = 0; ks < 4; ++ks) {
        int row = ni * 16 + l15;
        int slot = (ks * 4 + quad) ^ (row & 15);
        bf16x8 kf = *(const bf16x8*)&Ks[row * 128 + slot * 8];
        s[ni] = __builtin_amdgcn_mfma_f32_16x16x32_bf16(qf[ks], kf, s[ni], 0, 0, 0);
      }
    }
    const bool diag = (kt == qtile);
#pragma unroll
    for (int ni = 0; ni < 4; ++ni)
#pragma unroll
      for (int r = 0; r < 4; ++r) {
        float v = s[ni][r] * scale;
        if (diag && (ni * 16 + l15) > (w * 16 + quad * 4 + r)) v = -1e30f;
        s[ni][r] = v;
      }
    float mx[4], alpha[4], rs[4];
#pragma unroll
    for (int r = 0; r < 4; ++r)
      mx[r] = fmaxf(fmaxf(s[0][r], s[1][r]), fmaxf(s[2][r], s[3][r]));
#pragma unroll
    for (int off = 1; off < 16; off <<= 1)
#pragma unroll
      for (int r = 0; r < 4; ++r) mx[r] = fmaxf(mx[r], __shfl_xor(mx[r], off, 64));
    float ps[4][4];
#pragma unroll
    for (int r = 0; r < 4; ++r) {
      float mn = fmaxf(mrun[r], mx[r]);
      alpha[r] = __expf(mrun[r] - mn);
      mrun[r] = mn;
      rs[r] = 0.f;
    }
#pragma unroll
    for (int ni = 0; ni < 4; ++ni)
#pragma unroll
      for (int r = 0; r < 4; ++r) {
        float p = __expf(s[ni][r] - mrun[r]);
        ps[ni][r] = p;
        rs[r] += p;
      }
#pragma unroll
    for (int off = 1; off < 16; off <<= 1)
#pragma unroll
      for (int r = 0; r < 4; ++r) rs[r] += __shfl_xor(rs[r], off, 64);
#pragma unroll
    for (int r = 0; r < 4; ++r) lrun[r] = lrun[r] * alpha[r] + rs[r];
#pragma unroll
    for (int nt = 0; nt < 8; ++nt)
#pragma unroll
      for (int r = 0; r < 4; ++r) accO[nt][r] *= alpha[r];
#pragma unroll
    for (int ni = 0; ni < 4; ++ni)
#pragma unroll
      for (int r = 0; r < 4; ++r)
        Pw[(quad * 4 + r) * 72 + ni * 16 + l15] = (__bf16)ps[ni][r];
    asm volatile("s_waitcnt lgkmcnt(0)" ::: "memory");
    bf16x8 pf[2];
#pragma unroll
    for (int ks = 0; ks < 2; ++ks)
      pf[ks] = *(const bf16x8*)&Pw[l15 * 72 + ks * 32 + quad * 8];
#pragma unroll
    for (int nt = 0; nt < 8; ++nt)
#pragma unroll
      for (int ks = 0; ks < 2; ++ks) {
        int vrow = nt * 16 + l15;
        int slot = (ks * 4 + quad) ^ (vrow & 7);
        bf16x8 vf = *(const bf16x8*)&Vts[vrow * 64 + slot * 8];
        accO[nt] = __builtin_amdgcn_mfma_f32_16x16x32_bf16(pf[ks], vf, accO[nt], 0, 0, 0);
      }
  }

#pragma unroll
  for (int r = 0; r < 4; ++r) lrun[r] = 1.f / lrun[r];
#pragma unroll
  for (int nt = 0; nt < 8; ++nt)
#pragma unroll
    for (int r = 0; r < 4; ++r) {
      int trow = qtile * 64 + w * 16 + quad * 4 + r;
      int d = nt * 16 + l15;
      O[(size_t)(mrow_base + trow) * 4096 + h * 128 + d] =
          (__bf16)(accO[nt][r] * lrun[r]);
    }
}

extern "C" void kernel_launch(void* const* d_in, const int* in_sizes, int n_in,
                              void* d_out, int out_size, void* d_ws, size_t ws_size,
                              hipStream_t stream) {
  (void)in_sizes; (void)n_in; (void)out_size; (void)ws_size;
  const float* x = (const float*)d_in[0];
  const float* wq = (const float*)d_in[1];
  const float* wk = (const float*)d_in[2];
  const float* wv = (const float*)d_in[3];
  const float* wo = (const float*)d_in[4];
  float* out = (float*)d_out;

  const size_t SZ = (size_t)4096 * 4096;  // 16M elems; 9 bf16 arrays = 288 MB ws
  bf16_t* xb = (bf16_t*)d_ws;
  bf16_t* wqb = xb + SZ;
  bf16_t* wkb = wqb + SZ;
  bf16_t* wvb = wkb + SZ;
  bf16_t* wob = wvb + SZ;
  bf16_t* qb = wob + SZ;
  bf16_t* kb = qb + SZ;
  bf16_t* vtb = kb + SZ;
  bf16_t* ab = vtb + SZ;

  dim3 b256(256), b512(512);
  cast5_kernel<<<dim3((unsigned)(SZ / 8 / 256), 5), b256, 0, stream>>>(
      x, wq, wk, wv, wo, xb);

  gemm_qkv<<<dim3(256, 3), b512, 0, stream>>>(xb, wqb, wkb, wvb, qb, kb, vtb);

  attn_kernel<<<dim3(64, 32), b256, 0, stream>>>(qb, kb, vtb, ab);

  gemm_out<<<dim3(256), b512, 0, stream>>>(ab, wob, out);
}

// Round 7
// 970.531 us; speedup vs baseline: 1.1509x; 1.0085x over previous
//
#include <hip/hip_runtime.h>
#include <hip/hip_bf16.h>
#include <stdint.h>

// Problem constants: B=2, T=2048, C=4096, H=32, hd=128; M=N=K=4096 for all GEMMs.
typedef __bf16 bf16_t;
typedef __attribute__((ext_vector_type(8))) __bf16 bf16x8;
typedef __attribute__((ext_vector_type(4))) float f32x4;

// async global->LDS, 16B/lane; LDS dest is wave-uniform base + lane*16 (m104).
#define GLL16(gptr, lptr)                                                      \
  __builtin_amdgcn_global_load_lds(                                            \
      (__attribute__((address_space(1))) void*)(gptr),                         \
      (__attribute__((address_space(3))) void*)(lptr), 16, 0, 0)

// ---------------- fused f32 -> bf16 cast for all 5 tensors ----------------
__global__ __launch_bounds__(256) void cast5_kernel(const float* __restrict__ x,
                                                    const float* __restrict__ wq,
                                                    const float* __restrict__ wk,
                                                    const float* __restrict__ wv,
                                                    const float* __restrict__ wo,
                                                    bf16_t* __restrict__ outbase) {
  const size_t SZ = (size_t)4096 * 4096;
  const float* in;
  switch (blockIdx.y) {
    case 0: in = x; break;
    case 1: in = wq; break;
    case 2: in = wk; break;
    case 3: in = wv; break;
    default: in = wo; break;
  }
  bf16_t* out = outbase + (size_t)blockIdx.y * SZ;
  int i = blockIdx.x * 256 + threadIdx.x;  // 8 elems/thread
  const float4* p = (const float4*)in + (size_t)i * 2;
  float4 a = p[0], b = p[1];
  bf16x8 o;
  o[0] = (__bf16)a.x; o[1] = (__bf16)a.y; o[2] = (__bf16)a.z; o[3] = (__bf16)a.w;
  o[4] = (__bf16)b.x; o[5] = (__bf16)b.y; o[6] = (__bf16)b.z; o[7] = (__bf16)b.w;
  *((bf16x8*)out + i) = o;
}

// ================== 256x256 / BK=64 windowed GEMM machinery ==================
// (round-3 verified best: 420 us / MfmaUtil 44%.  Rounds 4-5's deeper custom
// pipelines both measured WORSE - plateau is structural.)
// LDS layout per operand: [buf][kk][256 rows][32 k-elems] bf16, 16 KB per
// (buf,kk) half-tile.  XOR swizzle (round-2, verified: bank conflicts -> 0):
// global k-chunk c of row r stored at slot c ^ ((r>>1)&3); reader slot
// quad ^ ((l15>>1)&3).  Swizzle applied on per-lane GLOBAL source address
// (GLL16 dest stays linear, m104); coalescing intact.
#define STAGE_HALF(gbase, ldsbase)                                             \
  do {                                                                         \
    GLL16((gbase) + (size_t)(w * 32 + sr) * 4096 + sq, (ldsbase) + w * 1024);  \
    GLL16((gbase) + (size_t)(w * 32 + 16 + sr) * 4096 + sq,                    \
          (ldsbase) + w * 1024 + 512);                                         \
  } while (0)

// One HALF = one (buf,kk) 16 KB pair of A/B quarter-tiles -> 32 MFMA.
// Read order pinned by sched_barrier(0) so the counted lgkmcnt(4) is exact:
//   [bfr x4, af0 x4 ds_reads][S1 GLLs (vmcnt only)] | [af1 x4 ds_reads]
//   lgkmcnt(4): bfr+af0 landed, af1 still in flight under MFMA cluster 1.
// Each inline-asm wait is followed by sched_barrier(0) (rule #18).
// Ends with a block barrier: protects next half's stage-writes against this
// half's reads.
#define HALF(buf_, kk_, S1_, S2_, TAIL_)                                       \
  do {                                                                         \
    bf16x8 af0_[4], af1_[4];                                                   \
    _Pragma("unroll") for (int ni = 0; ni < 4; ++ni) bfr[ni] =                 \
        *(const bf16x8*)&Bs[buf_][kk_][(wc * 64 + ni * 16 + l15) * 32 + sl8];  \
    _Pragma("unroll") for (int mi = 0; mi < 4; ++mi) af0_[mi] =                \
        *(const bf16x8*)&As[buf_][kk_][(wr * 128 + mi * 16 + l15) * 32 + sl8]; \
    S1_;                                                                       \
    __builtin_amdgcn_sched_barrier(0);                                         \
    _Pragma("unroll") for (int mi = 0; mi < 4; ++mi) af1_[mi] =                \
        *(const bf16x8*)&As[buf_][kk_][(wr * 128 + 64 + mi * 16 + l15) * 32 +  \
                                       sl8];                                   \
    asm volatile("s_waitcnt lgkmcnt(4)" ::: "memory");                         \
    __builtin_amdgcn_sched_barrier(0);                                         \
    __builtin_amdgcn_s_setprio(1);                                             \
    _Pragma("unroll") for (int mi = 0; mi < 4; ++mi)                           \
        _Pragma("unroll") for (int ni = 0; ni < 4; ++ni)                       \
            acc[mi][ni] = __builtin_amdgcn_mfma_f32_16x16x32_bf16(             \
                af0_[mi], bfr[ni], acc[mi][ni], 0, 0, 0);                      \
    __builtin_amdgcn_s_setprio(0);                                             \
    S2_;                                                                       \
    asm volatile("s_waitcnt lgkmcnt(0)" ::: "memory");                         \
    __builtin_amdgcn_sched_barrier(0);                                         \
    __builtin_amdgcn_s_setprio(1);                                             \
    _Pragma("unroll") for (int mi = 0; mi < 4; ++mi)                           \
        _Pragma("unroll") for (int ni = 0; ni < 4; ++ni)                       \
            acc[4 + mi][ni] = __builtin_amdgcn_mfma_f32_16x16x32_bf16(         \
                af1_[mi], bfr[ni], acc[4 + mi][ni], 0, 0, 0);                  \
    __builtin_amdgcn_s_setprio(0);                                             \
    TAIL_;                                                                     \
    __builtin_amdgcn_s_barrier();                                              \
  } while (0)

// Main loop: 2 windows (K-tiles) per iteration, 2 halves each = 4 barriers.
// Stage schedule per window of tile T:
//   half kk=0 stages (T+1, A-k1) and (T+1, B-k1)  [other-buf regions]
//   half kk=1 stages (T+2, A-k0) and (T+2, B-k0)  [this-buf kk0, read in half1]
// One counted vmcnt(4) per window; tail drains vmcnt(0) once.
#define GEMM256_MAIN(Aptr, Bptr)                                               \
  const bf16_t* Ag = (Aptr) + (size_t)bm * 4096;                               \
  const bf16_t* Bg = (Bptr) + (size_t)bn * 4096;                               \
  f32x4 acc[8][4] = {};                                                        \
  bf16x8 bfr[4];                                                               \
  STAGE_HALF(Ag, &As[0][0][0]);                                                \
  STAGE_HALF(Bg, &Bs[0][0][0]);                                                \
  STAGE_HALF(Ag + 32, &As[0][1][0]);                                           \
  STAGE_HALF(Bg + 32, &Bs[0][1][0]);                                           \
  STAGE_HALF(Ag + 64, &As[1][0][0]);                                           \
  STAGE_HALF(Bg + 64, &Bs[1][0][0]);                                           \
  asm volatile("s_waitcnt vmcnt(4)" ::: "memory");                             \
  __builtin_amdgcn_s_barrier();                                                \
  for (int it = 0; it < 32; ++it) {                                            \
    const int kt = it * 2;                                                     \
    const bool more = (it < 31);                                               \
    /* window buf0 = tile kt */                                                \
    HALF(0, 0,                                                                 \
         STAGE_HALF(Ag + (size_t)(kt + 1) * 64 + 32, &As[1][1][0]),            \
         STAGE_HALF(Bg + (size_t)(kt + 1) * 64 + 32, &Bs[1][1][0]), (void)0);  \
    HALF(0, 1,                                                                 \
         if (more) STAGE_HALF(Ag + (size_t)(kt + 2) * 64, &As[0][0][0]),       \
         if (more) STAGE_HALF(Bg + (size_t)(kt + 2) * 64, &Bs[0][0][0]),       \
         if (more) { asm volatile("s_waitcnt vmcnt(4)" ::: "memory"); } else { \
           asm volatile("s_waitcnt vmcnt(0)" ::: "memory"); });                \
    /* window buf1 = tile kt+1 */                                              \
    HALF(1, 0,                                                                 \
         if (more) STAGE_HALF(Ag + (size_t)(kt + 2) * 64 + 32, &As[0][1][0]),  \
         if (more) STAGE_HALF(Bg + (size_t)(kt + 2) * 64 + 32, &Bs[0][1][0]),  \
         (void)0);                                                             \
    HALF(1, 1,                                                                 \
         if (more) STAGE_HALF(Ag + (size_t)(kt + 3) * 64, &As[1][0][0]),       \
         if (more) STAGE_HALF(Bg + (size_t)(kt + 3) * 64, &Bs[1][0][0]),       \
         if (more) { asm volatile("s_waitcnt vmcnt(4)" ::: "memory"); });      \
  }

// ---------------- epilogues (8x4 accumulator geometry) ----------------
// C/D fragment mapping (16x16x32): row = quad*4 + reg, col = lane&15.
__device__ __forceinline__ void epi_rope256(const f32x4 (&acc)[8][4],
                                            bf16_t* __restrict__ C, int bm,
                                            int bn, int wr, int wc, int quad,
                                            int l15) {
#pragma unroll
  for (int a = 0; a < 8; ++a) {
    const int row0 = bm + wr * 128 + a * 16 + quad * 4;
    float fsv[4], fcv[4];
#pragma unroll
    for (int r = 0; r < 4; ++r)
      sincosf((float)((row0 + r) & 2047), &fsv[r], &fcv[r]);
#pragma unroll
    for (int ni = 0; ni < 4; ++ni) {
      const int col = bn + wc * 64 + ni * 16 + l15;
      const bool odd = (col & 1);
#pragma unroll
      for (int r = 0; r < 4; ++r) {
        float v = acc[a][ni][r];
        float pr = __shfl_xor(v, 1, 64);  // RoPE pair partner: adjacent col
        float o = odd ? (pr * fsv[r] + v * fcv[r]) : (v * fcv[r] - pr * fsv[r]);
        C[(size_t)(row0 + r) * 4096 + col] = (__bf16)o;
      }
    }
  }
}

__device__ __forceinline__ void epi_vt256(const f32x4 (&acc)[8][4],
                                          bf16_t* __restrict__ VT, int bm,
                                          int bn, int wr, int wc, int quad,
                                          int l15) {
#pragma unroll
  for (int a = 0; a < 8; ++a) {
    const int row0 = bm + wr * 128 + a * 16 + quad * 4;
    const int b = row0 >> 11, t0 = row0 & 2047;
#pragma unroll
    for (int ni = 0; ni < 4; ++ni) {
      const int col = bn + wc * 64 + ni * 16 + l15;
      const int h = col >> 7, d = col & 127;
      union { __bf16 e[4]; uint2 u; } pk;
#pragma unroll
      for (int r = 0; r < 4; ++r) pk.e[r] = (__bf16)acc[a][ni][r];
      *(uint2*)&VT[((size_t)((b * 32 + h) * 128 + d)) * 2048 + t0] = pk.u;
    }
  }
}

// ---------------- fused QKV projection: grid (256, 3) ----------------
__global__ __launch_bounds__(512, 2) void gemm_qkv(const bf16_t* __restrict__ X,
                                                   const bf16_t* __restrict__ WQ,
                                                   const bf16_t* __restrict__ WK,
                                                   const bf16_t* __restrict__ WV,
                                                   bf16_t* __restrict__ Qo,
                                                   bf16_t* __restrict__ Ko,
                                                   bf16_t* __restrict__ VTo) {
  __shared__ bf16_t As[2][2][8192];  // 64 KB
  __shared__ bf16_t Bs[2][2][8192];  // 64 KB
  const int tid = threadIdx.x;
  const int w = tid >> 6;
  const int lane = tid & 63;
  const int quad = lane >> 4;
  const int l15 = lane & 15;
  const int wr = w >> 2, wc = w & 3;              // 2M x 4N wave grid
  const int sr = lane >> 2;                       // stage row within 16
  const int sq = (((lane & 3) ^ ((lane >> 3) & 3))) * 8;  // swizzled k-chunk
  const int sl8 = (quad ^ ((l15 >> 1) & 3)) * 8;  // swizzled read slot
  const int mat = blockIdx.y;
  int id = blockIdx.x;
  id = (id & 7) * 32 + (id >> 3);  // XCD-aware swizzle (bijective: 256%8==0)
  const int bm = (id >> 4) * 256, bn = (id & 15) * 256;
  const bf16_t* Bp = (mat == 0) ? WQ : (mat == 1) ? WK : WV;

  GEMM256_MAIN(X, Bp)

  if (mat == 0)
    epi_rope256(acc, Qo, bm, bn, wr, wc, quad, l15);
  else if (mat == 1)
    epi_rope256(acc, Ko, bm, bn, wr, wc, quad, l15);
  else
    epi_vt256(acc, VTo, bm, bn, wr, wc, quad, l15);
}

// ---------------- output projection GEMM: f32 C row-major ----------------
__global__ __launch_bounds__(512, 2) void gemm_out(const bf16_t* __restrict__ A,
                                                   const bf16_t* __restrict__ B,
                                                   float* __restrict__ C) {
  __shared__ bf16_t As[2][2][8192];
  __shared__ bf16_t Bs[2][2][8192];
  const int tid = threadIdx.x;
  const int w = tid >> 6;
  const int lane = tid & 63;
  const int quad = lane >> 4;
  const int l15 = lane & 15;
  const int wr = w >> 2, wc = w & 3;
  const int sr = lane >> 2;
  const int sq = (((lane & 3) ^ ((lane >> 3) & 3))) * 8;
  const int sl8 = (quad ^ ((l15 >> 1) & 3)) * 8;
  int id = blockIdx.x;
  id = (id & 7) * 32 + (id >> 3);
  const int bm = (id >> 4) * 256, bn = (id & 15) * 256;

  GEMM256_MAIN(A, B)

#pragma unroll
  for (int a = 0; a < 8; ++a) {
    const int row0 = bm + wr * 128 + a * 16 + quad * 4;
#pragma unroll
    for (int ni = 0; ni < 4; ++ni) {
      const int col = bn + wc * 64 + ni * 16 + l15;
#pragma unroll
      for (int r = 0; r < 4; ++r)
        C[(size_t)(row0 + r) * 4096 + col] = acc[a][ni][r];
    }
  }
}

// ---------------- flash attention: 64x64 tiles, online softmax ----------------
// Double-buffered K/V (Ks[2],Vts[2]; LDS 80 KB -> 2 blocks/CU) with T3-minimum
// 2-phase schedule: per iter {vmcnt(0); s_barrier; issue next tile's 8 GLLs;
// compute cur}.  Staging drains under the full compute phase; 1 barrier/iter.
// Hazard proof: reads of buf cur^1 are consumed before each wave reaches the
// barrier; S(kt+1) is issued only after it.  Q staging is wave-private ->
// prologue needs only vmcnt(8) + own ds_reads, no barrier.
__global__ __launch_bounds__(256) void attn_kernel(const bf16_t* __restrict__ Q,
                                                   const bf16_t* __restrict__ Km,
                                                   const bf16_t* __restrict__ VT,
                                                   bf16_t* __restrict__ O) {
  __shared__ bf16_t Ks[2][64 * 128];   // 2 x 16 KB, swizzled
  __shared__ bf16_t Vts[2][128 * 64];  // 2 x 16 KB, swizzled
  __shared__ bf16_t QPs[64 * 128];     // 16 KB: Q staging, then P staging
  const int tid = threadIdx.x;
  const int w = tid >> 6;
  const int lane = tid & 63;
  const int quad = lane >> 4;
  const int l15 = lane & 15;
  const int bh = blockIdx.x;             // 0..63
  const int qtile = 31 - blockIdx.y;     // heavy tiles first (load balance)
  const int mrow_base = (bh >> 5) * 2048;
  const int h = bh & 31;
  const float scale = 0.08838834764831845f;  // 128^-0.5

// stage K tile kt -> Ks[BUF_], V tile kt -> Vts[BUF_]: 8 GLL16 per wave.
#define STAGE_KV(BUF_, KT_)                                                    \
  _Pragma("unroll") for (int it = 0; it < 4; ++it) {                           \
    int c = w * 4 + it;                                                        \
    int krow = c * 4 + (lane >> 4);                                            \
    int kcc = (lane & 15) ^ (krow & 15);                                       \
    GLL16(Km + (size_t)(mrow_base + (KT_)*64 + krow) * 4096 + h * 128 +        \
              kcc * 8,                                                         \
          &Ks[BUF_][c * 512]);                                                 \
    int vrow = c * 8 + (lane >> 3);                                            \
    int vcc = (lane & 7) ^ (vrow & 7);                                         \
    GLL16(VT + (size_t)(bh * 128 + vrow) * 2048 + (KT_)*64 + vcc * 8,          \
          &Vts[BUF_][c * 512]);                                                \
  }

  // ---- prologue: stage Q (wave-private rows) + K/V tile 0 ----
#pragma unroll
  for (int it = 0; it < 4; ++it) {
    int c = w * 4 + it;                 // 1KB chunk-group = 4 rows
    int row = c * 4 + (lane >> 4);
    int cc = (lane & 15) ^ (row & 15);  // global chunk for this lane's slot
    GLL16(Q + (size_t)(mrow_base + qtile * 64 + row) * 4096 + h * 128 + cc * 8,
          &QPs[c * 512]);
  }
  STAGE_KV(0, 0);                                      // 8 GLL (after Q's 4)
  asm volatile("s_waitcnt vmcnt(8)" ::: "memory");     // Q landed (wave-own)
  __builtin_amdgcn_sched_barrier(0);
  bf16x8 qf[4];  // wave's 16 q-rows, full hd=128, kept in regs
#pragma unroll
  for (int ks = 0; ks < 4; ++ks) {
    int row = w * 16 + l15;
    int slot = (ks * 4 + quad) ^ (row & 15);
    qf[ks] = *(const bf16x8*)&QPs[row * 128 + slot * 8];
  }
  asm volatile("s_waitcnt lgkmcnt(0)" ::: "memory");   // qf data fetched
  __builtin_amdgcn_sched_barrier(0);                   // QPs reusable for P
  bf16_t* Pw = &QPs[w * 16 * 72];  // wave-private P: 16 rows, stride 72 (pad)

  f32x4 accO[8] = {};
  float mrun[4], lrun[4];
#pragma unroll
  for (int r = 0; r < 4; ++r) { mrun[r] = -1e30f; lrun[r] = 0.f; }

  for (int kt = 0; kt <= qtile; ++kt) {
    const int cur = kt & 1;
    asm volatile("s_waitcnt vmcnt(0)" ::: "memory");   // S(kt) landed (own)
    __builtin_amdgcn_sched_barrier(0);
    __builtin_amdgcn_s_barrier();  // all waves' S(kt) visible; cur^1 reads done
    if (kt < qtile) { STAGE_KV(cur ^ 1, kt + 1); }     // drains under compute
    __builtin_amdgcn_sched_barrier(0);

    // S = Q K^T for wave's 16 rows x 64 cols
    f32x4 s[4];
#pragma unroll
    for (int ni = 0; ni < 4; ++ni) {
      s[ni] = (f32x4){0.f, 0.f, 0.f, 0.f};
#pragma unroll
      for (int ks = 0; ks < 4; ++ks) {
        int row = ni * 16 + l15;
        int slot = (ks * 4 + quad) ^ (row & 15);
        bf16x8 kf = *(const bf16x8*)&Ks[cur][row * 128 + slot * 8];
        s[ni] = __builtin_amdgcn_mfma_f32_16x16x32_bf16(qf[ks], kf, s[ni], 0, 0, 0);
      }
    }
    // scale + causal mask (only diagonal tile)
    const bool diag = (kt == qtile);
#pragma unroll
    for (int ni = 0; ni < 4; ++ni)
#pragma unroll
      for (int r = 0; r < 4; ++r) {
        float v = s[ni][r] * scale;
        if (diag && (ni * 16 + l15) > (w * 16 + quad * 4 + r)) v = -1e30f;
        s[ni][r] = v;
      }
    // online softmax (row groups = 16 lanes)
    float mx[4], alpha[4], rs[4];
#pragma unroll
    for (int r = 0; r < 4; ++r)
      mx[r] = fmaxf(fmaxf(s[0][r], s[1][r]), fmaxf(s[2][r], s[3][r]));
#pragma unroll
    for (int off = 1; off < 16; off <<= 1)
#pragma unroll
      for (int r = 0; r < 4; ++r) mx[r] = fmaxf(mx[r], __shfl_xor(mx[r], off, 64));
    float ps[4][4];
#pragma unroll
    for (int r = 0; r < 4; ++r) {
      float mn = fmaxf(mrun[r], mx[r]);
      alpha[r] = __expf(mrun[r] - mn);
      mrun[r] = mn;
      rs[r] = 0.f;
    }
#pragma unroll
    for (int ni = 0; ni < 4; ++ni)
#pragma unroll
      for (int r = 0; r < 4; ++r) {
        float p = __expf(s[ni][r] - mrun[r]);
        ps[ni][r] = p;
        rs[r] += p;
      }
#pragma unroll
    for (int off = 1; off < 16; off <<= 1)
#pragma unroll
      for (int r = 0; r < 4; ++r) rs[r] += __shfl_xor(rs[r], off, 64);
#pragma unroll
    for (int r = 0; r < 4; ++r) lrun[r] = lrun[r] * alpha[r] + rs[r];
#pragma unroll
    for (int nt = 0; nt < 8; ++nt)
#pragma unroll
      for (int r = 0; r < 4; ++r) accO[nt][r] *= alpha[r];
    // P: C-layout -> wave-private LDS (padded stride 72) -> A-operand layout
#pragma unroll
    for (int ni = 0; ni < 4; ++ni)
#pragma unroll
      for (int r = 0; r < 4; ++r)
        Pw[(quad * 4 + r) * 72 + ni * 16 + l15] = (__bf16)ps[ni][r];
    // wave-private region: wave-local LDS drain suffices (no block barrier)
    asm volatile("s_waitcnt lgkmcnt(0)" ::: "memory");
    __builtin_amdgcn_sched_barrier(0);
    bf16x8 pf[2];
#pragma unroll
    for (int ks = 0; ks < 2; ++ks)
      pf[ks] = *(const bf16x8*)&Pw[l15 * 72 + ks * 32 + quad * 8];
#pragma unroll
    for (int nt = 0; nt < 8; ++nt)
#pragma unroll
      for (int ks = 0; ks < 2; ++ks) {
        int vrow = nt * 16 + l15;
        int slot = (ks * 4 + quad) ^ (vrow & 7);
        bf16x8 vf = *(const bf16x8*)&Vts[cur][vrow * 64 + slot * 8];
        accO[nt] = __builtin_amdgcn_mfma_f32_16x16x32_bf16(pf[ks], vf, accO[nt], 0, 0, 0);
      }
  }

  // epilogue: O / l
#pragma unroll
  for (int r = 0; r < 4; ++r) lrun[r] = 1.f / lrun[r];
#pragma unroll
  for (int nt = 0; nt < 8; ++nt)
#pragma unroll
    for (int r = 0; r < 4; ++r) {
      int trow = qtile * 64 + w * 16 + quad * 4 + r;
      int d = nt * 16 + l15;
      O[(size_t)(mrow_base + trow) * 4096 + h * 128 + d] =
          (__bf16)(accO[nt][r] * lrun[r]);
    }
#undef STAGE_KV
}

extern "C" void kernel_launch(void* const* d_in, const int* in_sizes, int n_in,
                              void* d_out, int out_size, void* d_ws, size_t ws_size,
                              hipStream_t stream) {
  (void)in_sizes; (void)n_in; (void)out_size; (void)ws_size;
  const float* x = (const float*)d_in[0];
  const float* wq = (const float*)d_in[1];
  const float* wk = (const float*)d_in[2];
  const float* wv = (const float*)d_in[3];
  const float* wo = (const float*)d_in[4];
  float* out = (float*)d_out;

  const size_t SZ = (size_t)4096 * 4096;  // 16M elems; 9 bf16 arrays = 288 MB ws
  bf16_t* xb = (bf16_t*)d_ws;
  bf16_t* wqb = xb + SZ;
  bf16_t* wkb = wqb + SZ;
  bf16_t* wvb = wkb + SZ;
  bf16_t* wob = wvb + SZ;
  bf16_t* qb = wob + SZ;
  bf16_t* kb = qb + SZ;
  bf16_t* vtb = kb + SZ;
  bf16_t* ab = vtb + SZ;

  dim3 b256(256), b512(512);
  cast5_kernel<<<dim3((unsigned)(SZ / 8 / 256), 5), b256, 0, stream>>>(
      x, wq, wk, wv, wo, xb);

  gemm_qkv<<<dim3(256, 3), b512, 0, stream>>>(xb, wqb, wkb, wvb, qb, kb, vtb);

  attn_kernel<<<dim3(64, 32), b256, 0, stream>>>(qb, kb, vtb, ab);

  gemm_out<<<dim3(256), b512, 0, stream>>>(ab, wob, out);
}